// Round 2
// baseline (999.684 us; speedup 1.0000x reference)
//
#include <hip/hip_runtime.h>
#include <hip/hip_bf16.h>
#include <math.h>

// Problem constants
#define BB 2
#define TT 512
#define DM 1024
#define DI 2048
#define DCONV 4
#define NH 32
#define NS 32
#define DH 64
#define PROJW 4160   // 2*DI + NH*2
#define BT (BB*TT)   // 1024

__device__ __forceinline__ float sigmoidf_(float x) { return 1.0f / (1.0f + expf(-x)); }
__device__ __forceinline__ float siluf_(float x) { return x * sigmoidf_(x); }

// C[m,n] = sum_k A[m,k] * B[n,k]  (both row-major, K contiguous; "NT" layout)
template<int BM, int BN, int TM, int TN>
__global__ __launch_bounds__(256) void gemm_nt(const float* __restrict__ A,
                                               const float* __restrict__ B,
                                               float* __restrict__ C,
                                               int M, int N, int K) {
    constexpr int BK = 16;
    __shared__ float As[BK][BM];
    __shared__ float Bs[BK][BN];
    const int t = threadIdx.x;
    const int m0 = blockIdx.y * BM;
    const int n0 = blockIdx.x * BN;
    constexpr int NTX = BN / TN;          // threads along n
    const int tx = t % NTX;
    const int ty = t / NTX;

    float acc[TM][TN];
#pragma unroll
    for (int i = 0; i < TM; i++)
#pragma unroll
        for (int j = 0; j < TN; j++) acc[i][j] = 0.0f;

    for (int k0 = 0; k0 < K; k0 += BK) {
        // stage A tile (BM x BK) as As[k][m]
#pragma unroll
        for (int i = t; i < BM * 4; i += 256) {
            int row = i >> 2, kc = (i & 3) << 2;
            float4 v = *(const float4*)&A[(size_t)(m0 + row) * K + k0 + kc];
            As[kc + 0][row] = v.x; As[kc + 1][row] = v.y;
            As[kc + 2][row] = v.z; As[kc + 3][row] = v.w;
        }
#pragma unroll
        for (int i = t; i < BN * 4; i += 256) {
            int row = i >> 2, kc = (i & 3) << 2;
            float4 v = *(const float4*)&B[(size_t)(n0 + row) * K + k0 + kc];
            Bs[kc + 0][row] = v.x; Bs[kc + 1][row] = v.y;
            Bs[kc + 2][row] = v.z; Bs[kc + 3][row] = v.w;
        }
        __syncthreads();
#pragma unroll
        for (int k = 0; k < BK; k++) {
            float a[TM], b[TN];
#pragma unroll
            for (int i = 0; i < TM; i++) a[i] = As[k][ty * TM + i];
#pragma unroll
            for (int j = 0; j < TN; j++) b[j] = Bs[k][tx * TN + j];
#pragma unroll
            for (int i = 0; i < TM; i++)
#pragma unroll
                for (int j = 0; j < TN; j++)
                    acc[i][j] = fmaf(a[i], b[j], acc[i][j]);
        }
        __syncthreads();
    }
#pragma unroll
    for (int i = 0; i < TM; i++)
#pragma unroll
        for (int j = 0; j < TN; j++)
            C[(size_t)(m0 + ty * TM + i) * N + n0 + tx * TN + j] = acc[i][j];
}

// depthwise causal conv (K=4) over value_raw slice of proj, then SiLU
__global__ __launch_bounds__(256) void conv_silu_kernel(const float* __restrict__ proj,
                                                        const float* __restrict__ dw_w,
                                                        const float* __restrict__ dw_b,
                                                        float* __restrict__ value) {
    int idx = blockIdx.x * 256 + threadIdx.x;     // < BT*DI
    int di = idx & (DI - 1);
    int bt = idx >> 11;
    int t = bt & (TT - 1);
    const float* vr = proj + (size_t)bt * PROJW + DI + di;  // value_raw[bt][di]
    float4 w = *(const float4*)&dw_w[di * 4];
    float acc = dw_b[di];
    if (t >= 3) acc = fmaf(vr[-3 * PROJW], w.x, acc);
    if (t >= 2) acc = fmaf(vr[-2 * PROJW], w.y, acc);
    if (t >= 1) acc = fmaf(vr[-1 * PROJW], w.z, acc);
    acc = fmaf(vr[0], w.w, acc);
    value[idx] = siluf_(acc);
}

// per (bt,h,n): dt (softplus+clip), S = 1/(1 + dt*kd + dt^2*A)
__global__ __launch_bounds__(256) void dtkd_S_kernel(const float* __restrict__ proj,
                                                     const float* __restrict__ dt_bias,
                                                     const float* __restrict__ A_log,
                                                     float* __restrict__ dt_a,
                                                     float* __restrict__ S_a) {
    int idx = blockIdx.x * 256 + threadIdx.x;     // < BT*NH*NS
    int n = idx & (NS - 1);
    int h = (idx >> 5) & (NH - 1);
    int bt = idx >> 10;
    const float* prow = proj + (size_t)bt * PROJW + 2 * DI;
    float p0 = prow[2 * h], p1 = prow[2 * h + 1];
    float xdt = p0 + dt_bias[h];
    float sp = fmaxf(xdt, 0.0f) + log1pf(expf(-fabsf(xdt)));
    float dt = fminf(fmaxf(sp, 1e-4f), 0.1f);
    float kd = 0.5f * sigmoidf_(p1);
    float A = expf(A_log[h * NS + n]);
    float S = 1.0f / (1.0f + dt * kd + dt * dt * A);
    S_a[idx] = S;
    if (n == 0) dt_a[bt * NH + h] = dt;
}

// L2-normalize bc over groups of 32 (intra-32-lane shfl reduce)
__global__ __launch_bounds__(256) void normalize_kernel(float* __restrict__ bc) {
    int idx = blockIdx.x * 256 + threadIdx.x;     // < BT*4096
    float v = bc[idx];
    float ss = v * v;
    ss += __shfl_xor(ss, 1);
    ss += __shfl_xor(ss, 2);
    ss += __shfl_xor(ss, 4);
    ss += __shfl_xor(ss, 8);
    ss += __shfl_xor(ss, 16);
    bc[idx] = v / (sqrtf(ss) + 1e-8f);
}

// sequential scan: one block per (b,h); 256 threads = 4 waves;
// wave w owns d in [16w,16w+16); lane group ng = l>>4 owns n in [8*ng, 8*ng+8)
__global__ __launch_bounds__(256) void scan_kernel(const float* __restrict__ value,
                                                   const float* __restrict__ bc,
                                                   const float* __restrict__ dt_a,
                                                   const float* __restrict__ S_a,
                                                   const float* __restrict__ A_log,
                                                   float* __restrict__ yout) {
    const int bh = blockIdx.x;
    const int b = bh >> 5, h = bh & (NH - 1);
    const int tid = threadIdx.x;
    const int w = tid >> 6, l = tid & 63;
    const int d = w * 16 + (l & 15);
    const int ng = l >> 4;
    const int n0 = ng * 8;

    float a[8];
#pragma unroll
    for (int j = 0; j < 8; j++) a[j] = expf(A_log[h * NS + n0 + j]);

    float z[8], s[8];
#pragma unroll
    for (int j = 0; j < 8; j++) { z[j] = 0.0f; s[j] = 0.0f; }

    const float* vptr = value + (size_t)b * TT * DI + h * DH + d;
    const float* bcp  = bc + (size_t)b * TT * 4096 + h * 128 + n0;
    const float* dtp  = dt_a + (size_t)b * TT * NH + h;
    const float* Sp   = S_a + (size_t)b * TT * (NH * NS) + h * NS + n0;
    float* yp = yout + (size_t)b * TT * DI + h * DH + d;

    for (int t = 0; t < TT; t++) {
        float u_d = vptr[0];
        float dt = dtp[0];
        float bzv[8], bxv[8], czv[8], cxv[8], Sv[8];
        *(float4*)&bzv[0] = *(const float4*)&bcp[0];
        *(float4*)&bzv[4] = *(const float4*)&bcp[4];
        *(float4*)&bxv[0] = *(const float4*)&bcp[32];
        *(float4*)&bxv[4] = *(const float4*)&bcp[36];
        *(float4*)&czv[0] = *(const float4*)&bcp[64];
        *(float4*)&czv[4] = *(const float4*)&bcp[68];
        *(float4*)&cxv[0] = *(const float4*)&bcp[96];
        *(float4*)&cxv[4] = *(const float4*)&bcp[100];
        *(float4*)&Sv[0]  = *(const float4*)&Sp[0];
        *(float4*)&Sv[4]  = *(const float4*)&Sp[4];

        float dtu = dt * u_d;
        float y0 = 0.0f, y1 = 0.0f;
#pragma unroll
        for (int j = 0; j < 8; j++) {
            float dtA = dt * a[j];
            float t1 = fmaf(-dtA, s[j], z[j]);
            float t2 = fmaf(dtu, bzv[j], t1);
            float zn = Sv[j] * t2;
            z[j] = zn;
            float sn = fmaf(dt, zn, fmaf(dtu, bxv[j], s[j]));
            s[j] = sn;
            if (j & 1) { y1 = fmaf(czv[j], zn, y1); y1 = fmaf(cxv[j], sn, y1); }
            else       { y0 = fmaf(czv[j], zn, y0); y0 = fmaf(cxv[j], sn, y0); }
        }
        float y = y0 + y1;
        y += __shfl_xor(y, 16);
        y += __shfl_xor(y, 32);
        if (ng == 0) yp[0] = y;

        vptr += DI;
        bcp += 4096;
        dtp += NH;
        Sp += NH * NS;
        yp += DI;
    }
}

// y = (y + skip*value) * silu(gate)   (in place on yscan)
__global__ __launch_bounds__(256) void fuse_kernel(const float* __restrict__ proj,
                                                   const float* __restrict__ value,
                                                   const float* __restrict__ skip,
                                                   float* __restrict__ ysc) {
    int idx = blockIdx.x * 256 + threadIdx.x;     // < BT*DI
    int di = idx & (DI - 1);
    int bt = idx >> 11;
    float g = proj[(size_t)bt * PROJW + di];
    float yv = ysc[idx];
    float v = value[idx];
    ysc[idx] = fmaf(skip[di], v, yv) * siluf_(g);
}

extern "C" void kernel_launch(void* const* d_in, const int* in_sizes, int n_in,
                              void* d_out, int out_size, void* d_ws, size_t ws_size,
                              hipStream_t stream) {
    const float* x       = (const float*)d_in[0];
    const float* W_in    = (const float*)d_in[1];
    const float* dw_w    = (const float*)d_in[2];
    const float* dw_b    = (const float*)d_in[3];
    const float* W_bc    = (const float*)d_in[4];
    const float* W_out   = (const float*)d_in[5];
    const float* skip    = (const float*)d_in[6];
    const float* A_log   = (const float*)d_in[7];
    const float* dt_bias = (const float*)d_in[8];
    float* out = (float*)d_out;

    float* ws    = (float*)d_ws;
    float* proj  = ws;                       // BT*PROJW         = 4,259,840
    float* value = proj  + (size_t)BT * PROJW;        // BT*DI  = 2,097,152
    float* dt_a  = value + (size_t)BT * DI;           // BT*NH  = 32,768
    float* S_a   = dt_a  + (size_t)BT * NH;           // BT*NH*NS = 1,048,576
    float* bcw   = S_a   + (size_t)BT * NH * NS;      // BT*4096  = 4,194,304
    float* ysc   = bcw   + (size_t)BT * 4096;         // BT*DI    = 2,097,152

    dim3 blk(256);

    // 1) proj = x @ W_in^T : M=1024, N=4160, K=1024
    gemm_nt<128, 64, 8, 4><<<dim3(PROJW / 64, BT / 128), blk, 0, stream>>>(
        x, W_in, proj, BT, PROJW, DM);

    // 2) conv + silu -> value
    conv_silu_kernel<<<dim3(BT * DI / 256), blk, 0, stream>>>(proj, dw_w, dw_b, value);

    // 3) dt + S precompute
    dtkd_S_kernel<<<dim3(BT * NH * NS / 256), blk, 0, stream>>>(proj, dt_bias, A_log, dt_a, S_a);

    // 4) bc = value @ W_bc^T : M=1024, N=4096, K=2048
    gemm_nt<128, 64, 8, 4><<<dim3(4096 / 64, BT / 128), blk, 0, stream>>>(
        value, W_bc, bcw, BT, 4096, DI);

    // 5) normalize bc groups of 32
    normalize_kernel<<<dim3(BT * 4096 / 256), blk, 0, stream>>>(bcw);

    // 6) sequential scan
    scan_kernel<<<dim3(BB * NH), blk, 0, stream>>>(value, bcw, dt_a, S_a, A_log, ysc);

    // 7) fuse skip/gate
    fuse_kernel<<<dim3(BT * DI / 256), blk, 0, stream>>>(proj, value, skip, ysc);

    // 8) out = ysc @ W_out^T : M=1024, N=1024, K=2048
    gemm_nt<64, 64, 4, 4><<<dim3(DM / 64, BT / 64), blk, 0, stream>>>(
        ysc, W_out, out, BT, DM, DI);
}